// Round 12
// baseline (235.715 us; speedup 1.0000x reference)
//
#include <hip/hip_runtime.h>

#define N_NODES 50000
#define N_EDGES 800000
#define NBLK ((N_NODES + 63) / 64)     // 782
#define PAD 48          // Poisson(16): P(deg>=48)~1e-9; guarded
#define NBUCK 196       // dst>>8 -> 0..195
#define EBUCK 6144      // slots per bucket (avg 4082, >30 sigma headroom)

typedef __attribute__((ext_vector_type(8))) short bf16x8;
typedef __attribute__((ext_vector_type(4))) float f32x4;

__device__ __forceinline__ unsigned short f2bf(float f) {
  unsigned int u = __float_as_uint(f);
  unsigned int r = (u + 0x7fffu + ((u >> 16) & 1u)) >> 16;   // RNE
  return (unsigned short)r;
}
__device__ __forceinline__ float bf_lo(unsigned int p) { return __uint_as_float(p << 16); }
__device__ __forceinline__ float bf_hi(unsigned int p) { return __uint_as_float(p & 0xffff0000u); }

__device__ __forceinline__ bf16x8 ld_a_f32(const float* p) {
  float4 f0 = *(const float4*)p;
  float4 f1 = *(const float4*)(p + 4);
  bf16x8 a;
  a[0] = (short)f2bf(f0.x); a[1] = (short)f2bf(f0.y);
  a[2] = (short)f2bf(f0.z); a[3] = (short)f2bf(f0.w);
  a[4] = (short)f2bf(f1.x); a[5] = (short)f2bf(f1.y);
  a[6] = (short)f2bf(f1.z); a[7] = (short)f2bf(f1.w);
  return a;
}

__device__ __forceinline__ void fma8(float (&acc)[8], uint4 p, float w) {
  acc[0] += bf_lo(p.x) * w; acc[1] += bf_hi(p.x) * w;
  acc[2] += bf_lo(p.y) * w; acc[3] += bf_hi(p.y) * w;
  acc[4] += bf_lo(p.z) * w; acc[5] += bf_hi(p.z) * w;
  acc[6] += bf_lo(p.w) * w; acc[7] += bf_hi(p.w) * w;
}

// ---------------- merged: bucket partition | weight swizzle ----------------

__global__ __launch_bounds__(256)
void k_bp(const int* __restrict__ row, const int* __restrict__ col,
          int* __restrict__ bucket_ctr, unsigned int* __restrict__ bucketbuf,
          const float* __restrict__ gcn_W, const float* __restrict__ hW1,
          const float* __restrict__ cW1, const float* __restrict__ cW2,
          const float* __restrict__ hW2,
          unsigned short* __restrict__ gWs, unsigned short* __restrict__ hW1s,
          unsigned short* __restrict__ cW1s, unsigned short* __restrict__ cW2s,
          unsigned short* __restrict__ hW2s) {
  const int t = threadIdx.x;
  if (blockIdx.x < 196) {              // bucket role: 4096 edges per block
    __shared__ int cur[NBUCK];
    const int e0 = blockIdx.x * 4096;
    if (t < NBUCK) cur[t] = 0;
    __syncthreads();
    #pragma unroll
    for (int k = 0; k < 16; ++k) {
      int e = e0 + k * 256 + t;
      if (e < N_EDGES) atomicAdd(&cur[__builtin_nontemporal_load(&col[e]) >> 8], 1);
    }
    __syncthreads();
    if (t < NBUCK) {
      int h = cur[t];
      cur[t] = (h > 0) ? atomicAdd(&bucket_ctr[t], h) : 0;
    }
    __syncthreads();
    #pragma unroll
    for (int k = 0; k < 16; ++k) {
      int e = e0 + k * 256 + t;
      if (e < N_EDGES) {
        int c = __builtin_nontemporal_load(&col[e]);
        int b = c >> 8;
        int pos = atomicAdd(&cur[b], 1);
        if ((unsigned)pos < EBUCK)
          __builtin_nontemporal_store(
              (unsigned int)__builtin_nontemporal_load(&row[e]) | ((unsigned int)c << 16),
              &bucketbuf[(size_t)b * EBUCK + pos]);
      }
    }
    return;
  }
  // prep role: 196 blocks, first 64 lanes active
  const int bi = blockIdx.x - 196, l = t;
  if (l >= 64) return;
  const int g = l >> 4, li = l & 15;
  const float* src; unsigned short* dst; int Ncols, ks, nt;
  if (bi < 96) {                       // gcn_W: 3 layers x (4 ks x 8 nt)
    int layer = bi >> 5, rem = bi & 31; ks = rem >> 3; nt = rem & 7;
    src = gcn_W + layer * 16384; dst = gWs + layer * 16384 + (ks * 8 + nt) * 512; Ncols = 128;
  } else if (bi < 160) {               // head W1: 8 ks x 8 nt
    int rem = bi - 96; ks = rem >> 3; nt = rem & 7;
    src = hW1; dst = hW1s + (ks * 8 + nt) * 512; Ncols = 128;
  } else if (bi < 176) {               // ctx W1: 4 ks x 4 nt
    int rem = bi - 160; ks = rem >> 2; nt = rem & 3;
    src = cW1; dst = cW1s + (ks * 4 + nt) * 512; Ncols = 64;
  } else if (bi < 192) {               // ctx W2: 2 ks x 8 nt
    int rem = bi - 176; ks = rem >> 3; nt = rem & 7;
    src = cW2; dst = cW2s + (ks * 8 + nt) * 512; Ncols = 128;
  } else {                             // head W2: 4 ks, N=8 padded to 16
    ks = bi - 192; nt = 0;
    src = hW2; dst = hW2s + ks * 512; Ncols = 8;
  }
  #pragma unroll
  for (int e = 0; e < 8; ++e) {
    int k = ks * 32 + g * 8 + e, n = nt * 16 + li;
    dst[l * 8 + e] = (n < Ncols) ? f2bf(src[k * Ncols + n]) : (unsigned short)0;
  }
}

// ---------------- MFMA xform body (global A): outb = in @ Wsw ----------------

template<bool FP32IN>
__device__ __forceinline__ void xform_body(int bi, int t, const void* in,
                                           const unsigned short* Wsw,
                                           unsigned short* outb) {
  const int w = t >> 6, l = t & 63, g = l >> 4, li = l & 15;
  const int row = bi * 64 + w * 16 + li;
  const bool rowok = row < N_NODES;
  bf16x8 a[4];
  if (FP32IN) {
    const float* inf = (const float*)in;
    #pragma unroll
    for (int ks = 0; ks < 4; ++ks) {
      if (rowok) a[ks] = ld_a_f32(&inf[(size_t)row * 128 + ks * 32 + g * 8]);
      else       a[ks] = bf16x8{0,0,0,0,0,0,0,0};
    }
  } else {
    const unsigned short* inb = (const unsigned short*)in;
    #pragma unroll
    for (int ks = 0; ks < 4; ++ks) {
      if (rowok) a[ks] = *(const bf16x8*)&inb[(size_t)row * 128 + ks * 32 + g * 8];
      else       a[ks] = bf16x8{0,0,0,0,0,0,0,0};
    }
  }
  f32x4 acc[8];
  #pragma unroll
  for (int nt = 0; nt < 8; ++nt) acc[nt] = f32x4{0.f, 0.f, 0.f, 0.f};
  #pragma unroll
  for (int ks = 0; ks < 4; ++ks)
    #pragma unroll
    for (int nt = 0; nt < 8; ++nt) {
      bf16x8 b = *(const bf16x8*)&Wsw[((ks * 8 + nt) * 64 + l) * 8];
      acc[nt] = __builtin_amdgcn_mfma_f32_16x16x32_bf16(a[ks], b, acc[nt], 0, 0, 0);
    }
  const int orow0 = bi * 64 + w * 16 + g * 4;
  #pragma unroll
  for (int nt = 0; nt < 8; ++nt)
    #pragma unroll
    for (int r = 0; r < 4; ++r) {
      int orow = orow0 + r;
      if (orow < N_NODES) outb[(size_t)orow * 128 + nt * 16 + li] = f2bf(acc[nt][r]);
    }
}

// ---------------- ctx MLP body (MFMA 2-stage) ----------------

__device__ __forceinline__ void ctx_body(int bi, int t, const float* ctxn,
                                         const unsigned short* W1s, const float* b1,
                                         const unsigned short* W2s, const float* b2,
                                         unsigned short* outb,
                                         unsigned short (*mid)[16 * 64]) {
  const int w = t >> 6, l = t & 63, g = l >> 4, li = l & 15;
  const int row = bi * 64 + w * 16 + li;
  const bool rowok = row < N_NODES;
  bf16x8 a[4];
  #pragma unroll
  for (int ks = 0; ks < 4; ++ks) {
    if (rowok) a[ks] = ld_a_f32(&ctxn[(size_t)row * 128 + ks * 32 + g * 8]);
    else       a[ks] = bf16x8{0,0,0,0,0,0,0,0};
  }
  f32x4 acc1[4];
  #pragma unroll
  for (int nt = 0; nt < 4; ++nt) acc1[nt] = f32x4{0.f, 0.f, 0.f, 0.f};
  #pragma unroll
  for (int ks = 0; ks < 4; ++ks)
    #pragma unroll
    for (int nt = 0; nt < 4; ++nt) {
      bf16x8 b = *(const bf16x8*)&W1s[((ks * 4 + nt) * 64 + l) * 8];
      acc1[nt] = __builtin_amdgcn_mfma_f32_16x16x32_bf16(a[ks], b, acc1[nt], 0, 0, 0);
    }
  char* mb = (char*)&mid[w][0];
  #pragma unroll
  for (int nt = 0; nt < 4; ++nt)
    #pragma unroll
    for (int r = 0; r < 4; ++r) {
      int mrow = g * 4 + r, cn = nt * 16 + li;
      float v = fmaxf(acc1[nt][r] + b1[cn], 0.f);
      int boff = (mrow * 128 + cn * 2) ^ ((mrow & 7) << 4);
      *(unsigned short*)(mb + boff) = f2bf(v);
    }
  __syncthreads();
  bf16x8 a2[2];
  #pragma unroll
  for (int ks = 0; ks < 2; ++ks) {
    int boff = (li * 128 + ks * 64 + g * 16) ^ ((li & 7) << 4);
    a2[ks] = *(const bf16x8*)(mb + boff);
  }
  f32x4 acc2[8];
  #pragma unroll
  for (int nt = 0; nt < 8; ++nt) acc2[nt] = f32x4{0.f, 0.f, 0.f, 0.f};
  #pragma unroll
  for (int ks = 0; ks < 2; ++ks)
    #pragma unroll
    for (int nt = 0; nt < 8; ++nt) {
      bf16x8 b = *(const bf16x8*)&W2s[((ks * 8 + nt) * 64 + l) * 8];
      acc2[nt] = __builtin_amdgcn_mfma_f32_16x16x32_bf16(a2[ks], b, acc2[nt], 0, 0, 0);
    }
  const int orow0 = bi * 64 + w * 16 + g * 4;
  #pragma unroll
  for (int nt = 0; nt < 8; ++nt)
    #pragma unroll
    for (int r = 0; r < 4; ++r) {
      int orow = orow0 + r;
      if (orow < N_NODES)
        outb[(size_t)orow * 128 + nt * 16 + li] = f2bf(acc2[nt][r] + b2[nt * 16 + li]);
    }
}

// ---------------- front: build | xform0 | ctx ----------------

__global__ __launch_bounds__(256)
void k_front(const float* __restrict__ x, const unsigned short* __restrict__ gWs,
             unsigned short* __restrict__ hwbT,
             const float* __restrict__ ctxn, const unsigned short* __restrict__ cW1s,
             const float* __restrict__ cb1, const unsigned short* __restrict__ cW2s,
             const float* __restrict__ cb2, unsigned short* __restrict__ ctxb,
             const int* __restrict__ bucket_ctr, const unsigned int* __restrict__ bucketbuf,
             int* __restrict__ cnt, float* __restrict__ dinv,
             unsigned short* __restrict__ srcidx) {
  __shared__ unsigned short mid[4][16 * 64];
  const int bi = blockIdx.x, t = threadIdx.x;
  if (bi < 196) {                      // build role: per-bucket LDS-cursor adjacency
    __shared__ int lcur[256];
    lcur[t] = 0;
    __syncthreads();
    int n = bucket_ctr[bi];
    if (n < 0) n = 0;
    if (n > EBUCK) n = EBUCK;
    const unsigned int* buf = &bucketbuf[(size_t)bi * EBUCK];
    for (int i = t; i < n; i += 256) {
      unsigned int v = buf[i];
      int src = (int)(v & 0xffffu);
      int d   = (int)(v >> 16);
      int pos = atomicAdd(&lcur[d & 255], 1);
      if ((unsigned)pos < PAD) srcidx[(size_t)d * PAD + pos] = (unsigned short)src;
    }
    __syncthreads();
    int node = bi * 256 + t;
    if (node < N_NODES) {
      int c = lcur[t];
      cnt[node] = c;
      dinv[node] = rsqrtf((float)c + 1.0f);
    }
    return;
  }
  int gb = bi - 196;
  if (gb < NBLK) xform_body<true>(gb, t, x, gWs, hwbT);
  else           ctx_body(gb - NBLK, t, ctxn, cW1s, cb1, cW2s, cb2, ctxb, mid);
}

// ---------------- standalone agg: 3125 blocks, 4 nodes/wave, no LDS ----------------

__global__ __launch_bounds__(256)
void k_agg(const unsigned short* __restrict__ hwb, const int* __restrict__ cnt,
           const float* __restrict__ dinv, const unsigned short* __restrict__ srcidx,
           const float* __restrict__ b, const float* __restrict__ g,
           const float* __restrict__ bln, unsigned short* __restrict__ h_out) {
  const int t = threadIdx.x;
  const int lane = t & 63;
  const int li = lane & 15, grp = lane >> 4;
  const int node = blockIdx.x * 16 + (t >> 6) * 4 + grp;  // 3125 * 16 == 50000 exactly
  int cv = cnt[node];
  int deg = cv > PAD ? PAD : cv;
  const float dn = dinv[node];
  float acc[8] = {};
  fma8(acc, *(const uint4*)&hwb[(size_t)node * 128 + li * 8], dn * dn);  // self-loop
  const size_t base = (size_t)node * PAD;
  for (int c0 = 0; c0 < deg; c0 += 16) {
    int idx = c0 + li;
    int s_l = node; float w_l = 0.f;
    if (idx < deg) { s_l = (int)srcidx[base + idx]; w_l = dinv[s_l] * dn; }
    int sA[8]; float wA[8]; uint4 pA[8];
    int sB[8]; float wB[8]; uint4 pB[8];
    #pragma unroll
    for (int j = 0; j < 8; ++j) { sA[j] = __shfl(s_l, j, 16); wA[j] = __shfl(w_l, j, 16); }
    #pragma unroll
    for (int j = 0; j < 8; ++j) pA[j] = *(const uint4*)&hwb[(size_t)sA[j] * 128 + li * 8];
    #pragma unroll
    for (int j = 0; j < 8; ++j) { sB[j] = __shfl(s_l, j + 8, 16); wB[j] = __shfl(w_l, j + 8, 16); }
    #pragma unroll
    for (int j = 0; j < 8; ++j) pB[j] = *(const uint4*)&hwb[(size_t)sB[j] * 128 + li * 8];
    #pragma unroll
    for (int j = 0; j < 8; ++j) fma8(acc, pA[j], wA[j]);
    #pragma unroll
    for (int j = 0; j < 8; ++j) fma8(acc, pB[j], wB[j]);
  }
  float4 bv0 = *(const float4*)&b[li * 8], bv1 = *(const float4*)&b[li * 8 + 4];
  acc[0] += bv0.x; acc[1] += bv0.y; acc[2] += bv0.z; acc[3] += bv0.w;
  acc[4] += bv1.x; acc[5] += bv1.y; acc[6] += bv1.z; acc[7] += bv1.w;
  float ssum = 0.f;
  #pragma unroll
  for (int e = 0; e < 8; ++e) ssum += acc[e];
  #pragma unroll
  for (int off = 1; off < 16; off <<= 1) ssum += __shfl_xor(ssum, off, 16);
  float mu = ssum * (1.0f / 128.0f);
  float vs = 0.f;
  #pragma unroll
  for (int e = 0; e < 8; ++e) { float d = acc[e] - mu; vs += d * d; }
  #pragma unroll
  for (int off = 1; off < 16; off <<= 1) vs += __shfl_xor(vs, off, 16);
  float rstd = rsqrtf(vs * (1.0f / 128.0f) + 1e-5f);
  float4 gv0 = *(const float4*)&g[li * 8], gv1 = *(const float4*)&g[li * 8 + 4];
  float4 bl0 = *(const float4*)&bln[li * 8], bl1 = *(const float4*)&bln[li * 8 + 4];
  float o[8];
  o[0] = fmaxf((acc[0] - mu) * rstd * gv0.x + bl0.x, 0.f);
  o[1] = fmaxf((acc[1] - mu) * rstd * gv0.y + bl0.y, 0.f);
  o[2] = fmaxf((acc[2] - mu) * rstd * gv0.z + bl0.z, 0.f);
  o[3] = fmaxf((acc[3] - mu) * rstd * gv0.w + bl0.w, 0.f);
  o[4] = fmaxf((acc[4] - mu) * rstd * gv1.x + bl1.x, 0.f);
  o[5] = fmaxf((acc[5] - mu) * rstd * gv1.y + bl1.y, 0.f);
  o[6] = fmaxf((acc[6] - mu) * rstd * gv1.z + bl1.z, 0.f);
  o[7] = fmaxf((acc[7] - mu) * rstd * gv1.w + bl1.w, 0.f);
  uint4 pk;
  pk.x = ((unsigned int)f2bf(o[1]) << 16) | f2bf(o[0]);
  pk.y = ((unsigned int)f2bf(o[3]) << 16) | f2bf(o[2]);
  pk.z = ((unsigned int)f2bf(o[5]) << 16) | f2bf(o[4]);
  pk.w = ((unsigned int)f2bf(o[7]) << 16) | f2bf(o[6]);
  *(uint4*)&h_out[(size_t)node * 128 + li * 8] = pk;
}

// ---------------- standalone xform for layers 1,2 ----------------

__global__ __launch_bounds__(256)
void k_xform(const unsigned short* __restrict__ in, const unsigned short* __restrict__ Wsw,
             unsigned short* __restrict__ outb) {
  xform_body<false>(blockIdx.x, threadIdx.x, in, Wsw, outb);
}

// ---------------- head (MFMA 2-stage, global reads) ----------------

__global__ __launch_bounds__(256)
void k_head(const unsigned short* __restrict__ hb, const unsigned short* __restrict__ ctxb,
            const unsigned short* __restrict__ W1s, const float* __restrict__ b1,
            const unsigned short* __restrict__ W2s, const float* __restrict__ b2,
            float* __restrict__ out) {
  __shared__ unsigned short mid[4][16 * 128];
  const int t = threadIdx.x;
  const int w = t >> 6, l = t & 63, g = l >> 4, li = l & 15;
  const int row = blockIdx.x * 64 + w * 16 + li;
  const bool rowok = row < N_NODES;
  bf16x8 a[8];
  #pragma unroll
  for (int ks = 0; ks < 4; ++ks) {
    if (rowok) {
      a[ks]     = *(const bf16x8*)&hb[(size_t)row * 128 + ks * 32 + g * 8];
      a[ks + 4] = *(const bf16x8*)&ctxb[(size_t)row * 128 + ks * 32 + g * 8];
    } else {
      a[ks] = bf16x8{0,0,0,0,0,0,0,0};
      a[ks + 4] = bf16x8{0,0,0,0,0,0,0,0};
    }
  }
  f32x4 acc[8];
  #pragma unroll
  for (int nt = 0; nt < 8; ++nt) acc[nt] = f32x4{0.f, 0.f, 0.f, 0.f};
  #pragma unroll
  for (int ks = 0; ks < 8; ++ks)
    #pragma unroll
    for (int nt = 0; nt < 8; ++nt) {
      bf16x8 bb = *(const bf16x8*)&W1s[((ks * 8 + nt) * 64 + l) * 8];
      acc[nt] = __builtin_amdgcn_mfma_f32_16x16x32_bf16(a[ks], bb, acc[nt], 0, 0, 0);
    }
  char* mb = (char*)&mid[w][0];
  #pragma unroll
  for (int nt = 0; nt < 8; ++nt)
    #pragma unroll
    for (int r = 0; r < 4; ++r) {
      int mrow = g * 4 + r, cn = nt * 16 + li;
      float v = fmaxf(acc[nt][r] + b1[cn], 0.f);
      int boff = (mrow * 256 + cn * 2) ^ ((mrow & 7) << 4);
      *(unsigned short*)(mb + boff) = f2bf(v);
    }
  __syncthreads();
  f32x4 acc2 = f32x4{0.f, 0.f, 0.f, 0.f};
  #pragma unroll
  for (int ks = 0; ks < 4; ++ks) {
    int boff = (li * 256 + ks * 64 + g * 16) ^ ((li & 7) << 4);
    bf16x8 a2 = *(const bf16x8*)(mb + boff);
    bf16x8 bb = *(const bf16x8*)&W2s[(ks * 64 + l) * 8];
    acc2 = __builtin_amdgcn_mfma_f32_16x16x32_bf16(a2, bb, acc2, 0, 0, 0);
  }
  if (li < 8) {
    const int orow0 = blockIdx.x * 64 + w * 16 + g * 4;
    float bb2 = b2[li];
    #pragma unroll
    for (int r = 0; r < 4; ++r) {
      int orow = orow0 + r;
      if (orow < N_NODES) out[(size_t)orow * 8 + li] = acc2[r] + bb2;
    }
  }
}

// ---------------- launch ----------------

extern "C" void kernel_launch(void* const* d_in, const int* in_sizes, int n_in,
                              void* d_out, int out_size, void* d_ws, size_t ws_size,
                              hipStream_t stream) {
  const float* x     = (const float*)d_in[0];
  const int*   ei    = (const int*)d_in[1];
  const int*   row   = ei;             // sources (gather)
  const int*   col   = ei + N_EDGES;   // targets (scatter)
  const float* ctxn  = (const float*)d_in[2];
  const float* gcn_W = (const float*)d_in[3];
  const float* gcn_b = (const float*)d_in[4];
  const float* ln_g  = (const float*)d_in[5];
  const float* ln_b  = (const float*)d_in[6];
  const float* cW1   = (const float*)d_in[7];
  const float* cb1   = (const float*)d_in[8];
  const float* cW2   = (const float*)d_in[9];
  const float* cb2   = (const float*)d_in[10];
  const float* hW1   = (const float*)d_in[11];
  const float* hb1   = (const float*)d_in[12];
  const float* hW2   = (const float*)d_in[13];
  const float* hb2   = (const float*)d_in[14];
  float* out = (float*)d_out;

  char* ws = (char*)d_ws;
  size_t off = 0;
  auto alloc = [&](size_t bytes) -> void* {
    void* p = ws + off;
    off = (off + bytes + 255) & ~(size_t)255;
    return p;
  };
  int*   cnt        = (int*)alloc((size_t)N_NODES * 4);
  float* dinv       = (float*)alloc((size_t)N_NODES * 4);
  int*   bucket_ctr = (int*)alloc(512 * 4);
  unsigned int* bucketbuf = (unsigned int*)alloc((size_t)NBUCK * EBUCK * 4);
  unsigned short* srcidx = (unsigned short*)alloc((size_t)N_NODES * PAD * 2);
  unsigned short* hwbT = (unsigned short*)alloc((size_t)N_NODES * 128 * 2);  // transform out
  unsigned short* hbuf = (unsigned short*)alloc((size_t)N_NODES * 128 * 2);  // agg out
  unsigned short* ctxb = (unsigned short*)alloc((size_t)N_NODES * 128 * 2);
  unsigned short* gWs  = (unsigned short*)alloc((size_t)3 * 16384 * 2);
  unsigned short* hW1s = (unsigned short*)alloc((size_t)32768 * 2);
  unsigned short* cW1s = (unsigned short*)alloc((size_t)8192 * 2);
  unsigned short* cW2s = (unsigned short*)alloc((size_t)8192 * 2);
  unsigned short* hW2s = (unsigned short*)alloc((size_t)2048 * 2);

  hipMemsetAsync(bucket_ctr, 0, 512 * 4, stream);
  k_bp<<<392, 256, 0, stream>>>(row, col, bucket_ctr, bucketbuf,
                                gcn_W, hW1, cW1, cW2, hW2, gWs, hW1s, cW1s, cW2s, hW2s);
  k_front<<<196 + 2 * NBLK, 256, 0, stream>>>(x, gWs, hwbT, ctxn, cW1s, cb1, cW2s, cb2,
                                              ctxb, bucket_ctr, bucketbuf, cnt, dinv, srcidx);
  // layer0
  k_agg<<<N_NODES / 16, 256, 0, stream>>>(hwbT, cnt, dinv, srcidx, gcn_b, ln_g, ln_b, hbuf);
  k_xform<<<NBLK, 256, 0, stream>>>(hbuf, gWs + (size_t)1 * 16384, hwbT);
  // layer1
  k_agg<<<N_NODES / 16, 256, 0, stream>>>(hwbT, cnt, dinv, srcidx, gcn_b + 128, ln_g + 128,
                                          ln_b + 128, hbuf);
  k_xform<<<NBLK, 256, 0, stream>>>(hbuf, gWs + (size_t)2 * 16384, hwbT);
  // layer2
  k_agg<<<N_NODES / 16, 256, 0, stream>>>(hwbT, cnt, dinv, srcidx, gcn_b + 256, ln_g + 256,
                                          ln_b + 256, hbuf);
  k_head<<<NBLK, 256, 0, stream>>>(hbuf, ctxb, hW1s, hb1, hW2s, hb2, out);
}

// Round 13
// 196.060 us; speedup vs baseline: 1.2023x; 1.2023x over previous
//
#include <hip/hip_runtime.h>

#define N_NODES 50000
#define N_EDGES 800000
#define NBLK ((N_NODES + 63) / 64)     // 782
#define PAD 48          // Poisson(16): P(deg>=48)~1e-9; guarded
#define NBUCK 196       // dst>>8 -> 0..195
#define EBUCK 6144      // slots per bucket (avg 4082, >30 sigma headroom)
#define AGBLK (N_NODES / 16)           // 3125, 16 nodes per block

typedef __attribute__((ext_vector_type(8))) short bf16x8;
typedef __attribute__((ext_vector_type(4))) float f32x4;

__device__ __forceinline__ unsigned short f2bf(float f) {
  unsigned int u = __float_as_uint(f);
  unsigned int r = (u + 0x7fffu + ((u >> 16) & 1u)) >> 16;   // RNE
  return (unsigned short)r;
}
__device__ __forceinline__ float bf_lo(unsigned int p) { return __uint_as_float(p << 16); }
__device__ __forceinline__ float bf_hi(unsigned int p) { return __uint_as_float(p & 0xffff0000u); }

__device__ __forceinline__ bf16x8 ld_a_f32(const float* p) {
  float4 f0 = *(const float4*)p;
  float4 f1 = *(const float4*)(p + 4);
  bf16x8 a;
  a[0] = (short)f2bf(f0.x); a[1] = (short)f2bf(f0.y);
  a[2] = (short)f2bf(f0.z); a[3] = (short)f2bf(f0.w);
  a[4] = (short)f2bf(f1.x); a[5] = (short)f2bf(f1.y);
  a[6] = (short)f2bf(f1.z); a[7] = (short)f2bf(f1.w);
  return a;
}

__device__ __forceinline__ void fma8(float (&acc)[8], uint4 p, float w) {
  acc[0] += bf_lo(p.x) * w; acc[1] += bf_hi(p.x) * w;
  acc[2] += bf_lo(p.y) * w; acc[3] += bf_hi(p.y) * w;
  acc[4] += bf_lo(p.z) * w; acc[5] += bf_hi(p.z) * w;
  acc[6] += bf_lo(p.w) * w; acc[7] += bf_hi(p.w) * w;
}

// ---------------- merged: bucket partition | weight swizzle ----------------

__global__ __launch_bounds__(256)
void k_bp(const int* __restrict__ row, const int* __restrict__ col,
          int* __restrict__ bucket_ctr, unsigned int* __restrict__ bucketbuf,
          const float* __restrict__ gcn_W, const float* __restrict__ hW1,
          const float* __restrict__ cW1, const float* __restrict__ cW2,
          const float* __restrict__ hW2,
          unsigned short* __restrict__ gWs, unsigned short* __restrict__ hW1s,
          unsigned short* __restrict__ cW1s, unsigned short* __restrict__ cW2s,
          unsigned short* __restrict__ hW2s) {
  const int t = threadIdx.x;
  if (blockIdx.x < 196) {              // bucket role: 4096 edges per block
    __shared__ int cur[NBUCK];
    const int e0 = blockIdx.x * 4096;
    if (t < NBUCK) cur[t] = 0;
    __syncthreads();
    #pragma unroll
    for (int k = 0; k < 16; ++k) {
      int e = e0 + k * 256 + t;
      if (e < N_EDGES) atomicAdd(&cur[__builtin_nontemporal_load(&col[e]) >> 8], 1);
    }
    __syncthreads();
    if (t < NBUCK) {
      int h = cur[t];
      cur[t] = (h > 0) ? atomicAdd(&bucket_ctr[t], h) : 0;
    }
    __syncthreads();
    #pragma unroll
    for (int k = 0; k < 16; ++k) {
      int e = e0 + k * 256 + t;
      if (e < N_EDGES) {
        int c = __builtin_nontemporal_load(&col[e]);
        int b = c >> 8;
        int pos = atomicAdd(&cur[b], 1);
        if ((unsigned)pos < EBUCK)
          __builtin_nontemporal_store(
              (unsigned int)__builtin_nontemporal_load(&row[e]) | ((unsigned int)c << 16),
              &bucketbuf[(size_t)b * EBUCK + pos]);
      }
    }
    return;
  }
  // prep role: 196 blocks, first 64 lanes active
  const int bi = blockIdx.x - 196, l = t;
  if (l >= 64) return;
  const int g = l >> 4, li = l & 15;
  const float* src; unsigned short* dst; int Ncols, ks, nt;
  if (bi < 96) {                       // gcn_W: 3 layers x (4 ks x 8 nt)
    int layer = bi >> 5, rem = bi & 31; ks = rem >> 3; nt = rem & 7;
    src = gcn_W + layer * 16384; dst = gWs + layer * 16384 + (ks * 8 + nt) * 512; Ncols = 128;
  } else if (bi < 160) {               // head W1: 8 ks x 8 nt
    int rem = bi - 96; ks = rem >> 3; nt = rem & 7;
    src = hW1; dst = hW1s + (ks * 8 + nt) * 512; Ncols = 128;
  } else if (bi < 176) {               // ctx W1: 4 ks x 4 nt
    int rem = bi - 160; ks = rem >> 2; nt = rem & 3;
    src = cW1; dst = cW1s + (ks * 4 + nt) * 512; Ncols = 64;
  } else if (bi < 192) {               // ctx W2: 2 ks x 8 nt
    int rem = bi - 176; ks = rem >> 3; nt = rem & 7;
    src = cW2; dst = cW2s + (ks * 8 + nt) * 512; Ncols = 128;
  } else {                             // head W2: 4 ks, N=8 padded to 16
    ks = bi - 192; nt = 0;
    src = hW2; dst = hW2s + ks * 512; Ncols = 8;
  }
  #pragma unroll
  for (int e = 0; e < 8; ++e) {
    int k = ks * 32 + g * 8 + e, n = nt * 16 + li;
    dst[l * 8 + e] = (n < Ncols) ? f2bf(src[k * Ncols + n]) : (unsigned short)0;
  }
}

// ---------------- MFMA xform body (global A): outb = in @ Wsw ----------------

template<bool FP32IN>
__device__ __forceinline__ void xform_body(int bi, int t, const void* in,
                                           const unsigned short* Wsw,
                                           unsigned short* outb) {
  const int w = t >> 6, l = t & 63, g = l >> 4, li = l & 15;
  const int row = bi * 64 + w * 16 + li;
  const bool rowok = row < N_NODES;
  bf16x8 a[4];
  if (FP32IN) {
    const float* inf = (const float*)in;
    #pragma unroll
    for (int ks = 0; ks < 4; ++ks) {
      if (rowok) a[ks] = ld_a_f32(&inf[(size_t)row * 128 + ks * 32 + g * 8]);
      else       a[ks] = bf16x8{0,0,0,0,0,0,0,0};
    }
  } else {
    const unsigned short* inb = (const unsigned short*)in;
    #pragma unroll
    for (int ks = 0; ks < 4; ++ks) {
      if (rowok) a[ks] = *(const bf16x8*)&inb[(size_t)row * 128 + ks * 32 + g * 8];
      else       a[ks] = bf16x8{0,0,0,0,0,0,0,0};
    }
  }
  f32x4 acc[8];
  #pragma unroll
  for (int nt = 0; nt < 8; ++nt) acc[nt] = f32x4{0.f, 0.f, 0.f, 0.f};
  #pragma unroll
  for (int ks = 0; ks < 4; ++ks)
    #pragma unroll
    for (int nt = 0; nt < 8; ++nt) {
      bf16x8 b = *(const bf16x8*)&Wsw[((ks * 8 + nt) * 64 + l) * 8];
      acc[nt] = __builtin_amdgcn_mfma_f32_16x16x32_bf16(a[ks], b, acc[nt], 0, 0, 0);
    }
  const int orow0 = bi * 64 + w * 16 + g * 4;
  #pragma unroll
  for (int nt = 0; nt < 8; ++nt)
    #pragma unroll
    for (int r = 0; r < 4; ++r) {
      int orow = orow0 + r;
      if (orow < N_NODES) outb[(size_t)orow * 128 + nt * 16 + li] = f2bf(acc[nt][r]);
    }
}

// ---------------- ctx MLP body (MFMA 2-stage) ----------------

__device__ __forceinline__ void ctx_body(int bi, int t, const float* ctxn,
                                         const unsigned short* W1s, const float* b1,
                                         const unsigned short* W2s, const float* b2,
                                         unsigned short* outb,
                                         unsigned short (*mid)[16 * 64]) {
  const int w = t >> 6, l = t & 63, g = l >> 4, li = l & 15;
  const int row = bi * 64 + w * 16 + li;
  const bool rowok = row < N_NODES;
  bf16x8 a[4];
  #pragma unroll
  for (int ks = 0; ks < 4; ++ks) {
    if (rowok) a[ks] = ld_a_f32(&ctxn[(size_t)row * 128 + ks * 32 + g * 8]);
    else       a[ks] = bf16x8{0,0,0,0,0,0,0,0};
  }
  f32x4 acc1[4];
  #pragma unroll
  for (int nt = 0; nt < 4; ++nt) acc1[nt] = f32x4{0.f, 0.f, 0.f, 0.f};
  #pragma unroll
  for (int ks = 0; ks < 4; ++ks)
    #pragma unroll
    for (int nt = 0; nt < 4; ++nt) {
      bf16x8 b = *(const bf16x8*)&W1s[((ks * 4 + nt) * 64 + l) * 8];
      acc1[nt] = __builtin_amdgcn_mfma_f32_16x16x32_bf16(a[ks], b, acc1[nt], 0, 0, 0);
    }
  char* mb = (char*)&mid[w][0];
  #pragma unroll
  for (int nt = 0; nt < 4; ++nt)
    #pragma unroll
    for (int r = 0; r < 4; ++r) {
      int mrow = g * 4 + r, cn = nt * 16 + li;
      float v = fmaxf(acc1[nt][r] + b1[cn], 0.f);
      int boff = (mrow * 128 + cn * 2) ^ ((mrow & 7) << 4);
      *(unsigned short*)(mb + boff) = f2bf(v);
    }
  __syncthreads();
  bf16x8 a2[2];
  #pragma unroll
  for (int ks = 0; ks < 2; ++ks) {
    int boff = (li * 128 + ks * 64 + g * 16) ^ ((li & 7) << 4);
    a2[ks] = *(const bf16x8*)(mb + boff);
  }
  f32x4 acc2[8];
  #pragma unroll
  for (int nt = 0; nt < 8; ++nt) acc2[nt] = f32x4{0.f, 0.f, 0.f, 0.f};
  #pragma unroll
  for (int ks = 0; ks < 2; ++ks)
    #pragma unroll
    for (int nt = 0; nt < 8; ++nt) {
      bf16x8 b = *(const bf16x8*)&W2s[((ks * 8 + nt) * 64 + l) * 8];
      acc2[nt] = __builtin_amdgcn_mfma_f32_16x16x32_bf16(a2[ks], b, acc2[nt], 0, 0, 0);
    }
  const int orow0 = bi * 64 + w * 16 + g * 4;
  #pragma unroll
  for (int nt = 0; nt < 8; ++nt)
    #pragma unroll
    for (int r = 0; r < 4; ++r) {
      int orow = orow0 + r;
      if (orow < N_NODES)
        outb[(size_t)orow * 128 + nt * 16 + li] = f2bf(acc2[nt][r] + b2[nt * 16 + li]);
    }
}

// ---------------- front: build | xform0 | ctx ----------------

__global__ __launch_bounds__(256)
void k_front(const float* __restrict__ x, const unsigned short* __restrict__ gWs,
             unsigned short* __restrict__ hwbT,
             const float* __restrict__ ctxn, const unsigned short* __restrict__ cW1s,
             const float* __restrict__ cb1, const unsigned short* __restrict__ cW2s,
             const float* __restrict__ cb2, unsigned short* __restrict__ ctxb,
             const int* __restrict__ bucket_ctr, const unsigned int* __restrict__ bucketbuf,
             int* __restrict__ cnt, float* __restrict__ dinv,
             unsigned short* __restrict__ srcidx) {
  __shared__ unsigned short mid[4][16 * 64];
  const int bi = blockIdx.x, t = threadIdx.x;
  if (bi < 196) {                      // build role: per-bucket LDS-cursor adjacency
    __shared__ int lcur[256];
    lcur[t] = 0;
    __syncthreads();
    int n = bucket_ctr[bi];
    if (n < 0) n = 0;
    if (n > EBUCK) n = EBUCK;
    const unsigned int* buf = &bucketbuf[(size_t)bi * EBUCK];
    for (int i = t; i < n; i += 256) {
      unsigned int v = buf[i];
      int src = (int)(v & 0xffffu);
      int d   = (int)(v >> 16);
      int pos = atomicAdd(&lcur[d & 255], 1);
      if ((unsigned)pos < PAD) srcidx[(size_t)d * PAD + pos] = (unsigned short)src;
    }
    __syncthreads();
    int node = bi * 256 + t;
    if (node < N_NODES) {
      int c = lcur[t];
      cnt[node] = c;
      dinv[node] = rsqrtf((float)c + 1.0f);
    }
    return;
  }
  int gb = bi - 196;
  if (gb < NBLK) xform_body<true>(gb, t, x, gWs, hwbT);
  else           ctx_body(gb - NBLK, t, ctxn, cW1s, cb1, cW2s, cb2, ctxb, mid);
}

// ---------------- agg phase: 1 node per 16-lane group, 16 nodes -> 4KB LDS tile ----------------

__device__ __forceinline__ void agg16(int base16, int t,
    const unsigned short* __restrict__ hwb, const int* __restrict__ cnt,
    const float* __restrict__ dinv, const unsigned short* __restrict__ srcidx,
    const float* __restrict__ b, const float* __restrict__ g,
    const float* __restrict__ bln, char* hl) {
  const int w = t >> 6, lane = t & 63, li = lane & 15, grp = lane >> 4;
  const int r = w * 4 + grp;                 // 0..15
  const int node = base16 + r;               // always < N_NODES (3125*16 == 50000)
  int cv = cnt[node];
  int deg = cv > PAD ? PAD : cv;
  const float dn = dinv[node];
  float acc[8] = {};
  fma8(acc, *(const uint4*)&hwb[(size_t)node * 128 + li * 8], dn * dn);  // self-loop
  const size_t sbase = (size_t)node * PAD;
  for (int c0 = 0; c0 < deg; c0 += 16) {
    int idx = c0 + li;
    int s_l = node; float w_l = 0.f;
    if (idx < deg) { s_l = (int)srcidx[sbase + idx]; w_l = dinv[s_l] * dn; }
    int sA[8]; float wA[8]; uint4 pA[8];
    int sB[8]; float wB[8]; uint4 pB[8];
    #pragma unroll
    for (int j = 0; j < 8; ++j) { sA[j] = __shfl(s_l, j, 16); wA[j] = __shfl(w_l, j, 16); }
    #pragma unroll
    for (int j = 0; j < 8; ++j) pA[j] = *(const uint4*)&hwb[(size_t)sA[j] * 128 + li * 8];
    #pragma unroll
    for (int j = 0; j < 8; ++j) { sB[j] = __shfl(s_l, j + 8, 16); wB[j] = __shfl(w_l, j + 8, 16); }
    #pragma unroll
    for (int j = 0; j < 8; ++j) pB[j] = *(const uint4*)&hwb[(size_t)sB[j] * 128 + li * 8];
    #pragma unroll
    for (int j = 0; j < 8; ++j) fma8(acc, pA[j], wA[j]);
    #pragma unroll
    for (int j = 0; j < 8; ++j) fma8(acc, pB[j], wB[j]);
  }
  float4 bv0 = *(const float4*)&b[li * 8], bv1 = *(const float4*)&b[li * 8 + 4];
  acc[0] += bv0.x; acc[1] += bv0.y; acc[2] += bv0.z; acc[3] += bv0.w;
  acc[4] += bv1.x; acc[5] += bv1.y; acc[6] += bv1.z; acc[7] += bv1.w;
  float ssum = 0.f;
  #pragma unroll
  for (int e = 0; e < 8; ++e) ssum += acc[e];
  #pragma unroll
  for (int off = 1; off < 16; off <<= 1) ssum += __shfl_xor(ssum, off, 16);
  float mu = ssum * (1.0f / 128.0f);
  float vs = 0.f;
  #pragma unroll
  for (int e = 0; e < 8; ++e) { float d = acc[e] - mu; vs += d * d; }
  #pragma unroll
  for (int off = 1; off < 16; off <<= 1) vs += __shfl_xor(vs, off, 16);
  float rstd = rsqrtf(vs * (1.0f / 128.0f) + 1e-5f);
  float4 gv0 = *(const float4*)&g[li * 8], gv1 = *(const float4*)&g[li * 8 + 4];
  float4 bl0 = *(const float4*)&bln[li * 8], bl1 = *(const float4*)&bln[li * 8 + 4];
  float o[8];
  o[0] = fmaxf((acc[0] - mu) * rstd * gv0.x + bl0.x, 0.f);
  o[1] = fmaxf((acc[1] - mu) * rstd * gv0.y + bl0.y, 0.f);
  o[2] = fmaxf((acc[2] - mu) * rstd * gv0.z + bl0.z, 0.f);
  o[3] = fmaxf((acc[3] - mu) * rstd * gv0.w + bl0.w, 0.f);
  o[4] = fmaxf((acc[4] - mu) * rstd * gv1.x + bl1.x, 0.f);
  o[5] = fmaxf((acc[5] - mu) * rstd * gv1.y + bl1.y, 0.f);
  o[6] = fmaxf((acc[6] - mu) * rstd * gv1.z + bl1.z, 0.f);
  o[7] = fmaxf((acc[7] - mu) * rstd * gv1.w + bl1.w, 0.f);
  uint4 pk;
  pk.x = ((unsigned int)f2bf(o[1]) << 16) | f2bf(o[0]);
  pk.y = ((unsigned int)f2bf(o[3]) << 16) | f2bf(o[2]);
  pk.z = ((unsigned int)f2bf(o[5]) << 16) | f2bf(o[4]);
  pk.w = ((unsigned int)f2bf(o[7]) << 16) | f2bf(o[6]);
  int boff = r * 256 + ((li * 16) ^ ((r & 7) << 4));
  *(uint4*)(hl + boff) = pk;
}

// ---------------- fused agg + xform(next layer): 3125 blocks, 16 rows, nt split by wave ----------------

__global__ __launch_bounds__(256)
void k_aggx(const unsigned short* __restrict__ hwb_in, const int* __restrict__ cnt,
            const float* __restrict__ dinv, const unsigned short* __restrict__ srcidx,
            const float* __restrict__ b, const float* __restrict__ g,
            const float* __restrict__ bln,
            const unsigned short* __restrict__ Wsw, unsigned short* __restrict__ hwb_out) {
  __shared__ char hl[16 * 256];
  const int t = threadIdx.x, base16 = blockIdx.x * 16;
  agg16(base16, t, hwb_in, cnt, dinv, srcidx, b, g, bln, hl);
  __syncthreads();
  const int w = t >> 6, l = t & 63, gq = l >> 4, li = l & 15;
  bf16x8 a[4];
  #pragma unroll
  for (int ks = 0; ks < 4; ++ks)
    a[ks] = *(const bf16x8*)(hl + li * 256 + ((ks * 64 + gq * 16) ^ ((li & 7) << 4)));
  f32x4 acc[2];
  acc[0] = f32x4{0.f, 0.f, 0.f, 0.f};
  acc[1] = f32x4{0.f, 0.f, 0.f, 0.f};
  #pragma unroll
  for (int ks = 0; ks < 4; ++ks)
    #pragma unroll
    for (int j = 0; j < 2; ++j) {
      int nt = w * 2 + j;
      bf16x8 bb = *(const bf16x8*)&Wsw[((ks * 8 + nt) * 64 + l) * 8];
      acc[j] = __builtin_amdgcn_mfma_f32_16x16x32_bf16(a[ks], bb, acc[j], 0, 0, 0);
    }
  const int orow0 = base16 + gq * 4;
  #pragma unroll
  for (int j = 0; j < 2; ++j) {
    int nt = w * 2 + j;
    #pragma unroll
    for (int r = 0; r < 4; ++r)
      hwb_out[(size_t)(orow0 + r) * 128 + nt * 16 + li] = f2bf(acc[j][r]);
  }
}

// ---------------- fused agg + head: 3125 blocks, 16 rows ----------------

__global__ __launch_bounds__(256)
void k_agghead(const unsigned short* __restrict__ hwb_in, const int* __restrict__ cnt,
               const float* __restrict__ dinv, const unsigned short* __restrict__ srcidx,
               const float* __restrict__ b, const float* __restrict__ g,
               const float* __restrict__ bln,
               const unsigned short* __restrict__ ctxb,
               const unsigned short* __restrict__ W1s, const float* __restrict__ b1,
               const unsigned short* __restrict__ W2s, const float* __restrict__ b2,
               float* __restrict__ out) {
  __shared__ char hl[16 * 256];
  __shared__ unsigned short mid[16 * 128];
  const int t = threadIdx.x, base16 = blockIdx.x * 16;
  agg16(base16, t, hwb_in, cnt, dinv, srcidx, b, g, bln, hl);
  __syncthreads();
  const int w = t >> 6, l = t & 63, gq = l >> 4, li = l & 15;
  bf16x8 a[8];
  #pragma unroll
  for (int ks = 0; ks < 4; ++ks) {
    a[ks] = *(const bf16x8*)(hl + li * 256 + ((ks * 64 + gq * 16) ^ ((li & 7) << 4)));
    a[ks + 4] = *(const bf16x8*)&ctxb[(size_t)(base16 + li) * 128 + ks * 32 + gq * 8];
  }
  f32x4 acc[2];
  acc[0] = f32x4{0.f, 0.f, 0.f, 0.f};
  acc[1] = f32x4{0.f, 0.f, 0.f, 0.f};
  #pragma unroll
  for (int ks = 0; ks < 8; ++ks)
    #pragma unroll
    for (int j = 0; j < 2; ++j) {
      int nt = w * 2 + j;
      bf16x8 bb = *(const bf16x8*)&W1s[((ks * 8 + nt) * 64 + l) * 8];
      acc[j] = __builtin_amdgcn_mfma_f32_16x16x32_bf16(a[ks], bb, acc[j], 0, 0, 0);
    }
  char* mb = (char*)&mid[0];
  #pragma unroll
  for (int j = 0; j < 2; ++j) {
    int nt = w * 2 + j;
    #pragma unroll
    for (int r = 0; r < 4; ++r) {
      int mrow = gq * 4 + r, cn = nt * 16 + li;
      float v = fmaxf(acc[j][r] + b1[cn], 0.f);
      int boff = (mrow * 256 + cn * 2) ^ ((mrow & 7) << 4);
      *(unsigned short*)(mb + boff) = f2bf(v);
    }
  }
  __syncthreads();
  if (w == 0) {
    f32x4 acc2 = f32x4{0.f, 0.f, 0.f, 0.f};
    #pragma unroll
    for (int ks = 0; ks < 4; ++ks) {
      int boff = (li * 256 + ks * 64 + gq * 16) ^ ((li & 7) << 4);
      bf16x8 a2 = *(const bf16x8*)(mb + boff);
      bf16x8 bb = *(const bf16x8*)&W2s[(ks * 64 + l) * 8];
      acc2 = __builtin_amdgcn_mfma_f32_16x16x32_bf16(a2, bb, acc2, 0, 0, 0);
    }
    if (li < 8) {
      const int orow0 = base16 + gq * 4;
      float bb2 = b2[li];
      #pragma unroll
      for (int r = 0; r < 4; ++r)
        out[(size_t)(orow0 + r) * 8 + li] = acc2[r] + bb2;
    }
  }
}

// ---------------- launch ----------------

extern "C" void kernel_launch(void* const* d_in, const int* in_sizes, int n_in,
                              void* d_out, int out_size, void* d_ws, size_t ws_size,
                              hipStream_t stream) {
  const float* x     = (const float*)d_in[0];
  const int*   ei    = (const int*)d_in[1];
  const int*   row   = ei;             // sources (gather)
  const int*   col   = ei + N_EDGES;   // targets (scatter)
  const float* ctxn  = (const float*)d_in[2];
  const float* gcn_W = (const float*)d_in[3];
  const float* gcn_b = (const float*)d_in[4];
  const float* ln_g  = (const float*)d_in[5];
  const float* ln_b  = (const float*)d_in[6];
  const float* cW1   = (const float*)d_in[7];
  const float* cb1   = (const float*)d_in[8];
  const float* cW2   = (const float*)d_in[9];
  const float* cb2   = (const float*)d_in[10];
  const float* hW1   = (const float*)d_in[11];
  const float* hb1   = (const float*)d_in[12];
  const float* hW2   = (const float*)d_in[13];
  const float* hb2   = (const float*)d_in[14];
  float* out = (float*)d_out;

  char* ws = (char*)d_ws;
  size_t off = 0;
  auto alloc = [&](size_t bytes) -> void* {
    void* p = ws + off;
    off = (off + bytes + 255) & ~(size_t)255;
    return p;
  };
  int*   cnt        = (int*)alloc((size_t)N_NODES * 4);
  float* dinv       = (float*)alloc((size_t)N_NODES * 4);
  int*   bucket_ctr = (int*)alloc(512 * 4);
  unsigned int* bucketbuf = (unsigned int*)alloc((size_t)NBUCK * EBUCK * 4);
  unsigned short* srcidx = (unsigned short*)alloc((size_t)N_NODES * PAD * 2);
  unsigned short* hwbA = (unsigned short*)alloc((size_t)N_NODES * 128 * 2);
  unsigned short* hwbB = (unsigned short*)alloc((size_t)N_NODES * 128 * 2);
  unsigned short* ctxb = (unsigned short*)alloc((size_t)N_NODES * 128 * 2);
  unsigned short* gWs  = (unsigned short*)alloc((size_t)3 * 16384 * 2);
  unsigned short* hW1s = (unsigned short*)alloc((size_t)32768 * 2);
  unsigned short* cW1s = (unsigned short*)alloc((size_t)8192 * 2);
  unsigned short* cW2s = (unsigned short*)alloc((size_t)8192 * 2);
  unsigned short* hW2s = (unsigned short*)alloc((size_t)2048 * 2);

  hipMemsetAsync(bucket_ctr, 0, 512 * 4, stream);
  k_bp<<<392, 256, 0, stream>>>(row, col, bucket_ctr, bucketbuf,
                                gcn_W, hW1, cW1, cW2, hW2, gWs, hW1s, cW1s, cW2s, hW2s);
  k_front<<<196 + 2 * NBLK, 256, 0, stream>>>(x, gWs, hwbA, ctxn, cW1s, cb1, cW2s, cb2,
                                              ctxb, bucket_ctr, bucketbuf, cnt, dinv, srcidx);
  // layer0: agg(hwbA) + xform(W1) -> hwbB
  k_aggx<<<AGBLK, 256, 0, stream>>>(hwbA, cnt, dinv, srcidx, gcn_b, ln_g, ln_b,
                                    gWs + (size_t)1 * 16384, hwbB);
  // layer1: agg(hwbB) + xform(W2) -> hwbA
  k_aggx<<<AGBLK, 256, 0, stream>>>(hwbB, cnt, dinv, srcidx, gcn_b + 128, ln_g + 128,
                                    ln_b + 128, gWs + (size_t)2 * 16384, hwbA);
  // layer2: agg(hwbA) + head -> out
  k_agghead<<<AGBLK, 256, 0, stream>>>(hwbA, cnt, dinv, srcidx, gcn_b + 256, ln_g + 256,
                                       ln_b + 256, ctxb, hW1s, hb1, hW2s, hb2, out);
}